// Round 7
// baseline (205.223 us; speedup 1.0000x reference)
//
#include <hip/hip_runtime.h>

#define NB 32
#define L2E 1.4426950408889634f

typedef float v2f __attribute__((ext_vector_type(2)));

static __device__ __forceinline__ float exp2f_fast(float x) {
#if __has_builtin(__builtin_amdgcn_exp2f)
    return __builtin_amdgcn_exp2f(x);
#else
    return __expf(x * 0.6931471805599453f);
#endif
}

#if __has_builtin(__builtin_elementwise_fma)
#define VFMA(a, b, c) __builtin_elementwise_fma(a, b, c)
#else
static __device__ inline v2f VFMA(v2f a, v2f b, v2f c) {
    v2f r; r.x = fmaf(a.x, b.x, c.x); r.y = fmaf(a.y, b.y, c.y); return r;
}
#endif

// Storage position p (0..31) -> basis index k (1-based). Pairing chosen so
// every 4th-power derivation maps a whole v2f pair onto a whole v2f pair
// (E_k = E_{2k}^4 since gamma_k = 32/k^2 exactly): zero shuffles.
// Positions 0..7 ("A half", pairs j=0..3) are the roots feeding the whole
// derive tree; positions 8..15 ("B half", j=4..7) are leaf roots.
static __device__ const int POS2K[NB] = {
    32,24, 28,20, 30,22, 26,18, 31,23, 29,21, 27,19, 25,17,
    16,12, 14,10, 15,11, 13,9,  8,6,   7,5,   4,3,   2,1 };

__global__ __launch_bounds__(256, 8) void gp_main(
    const float* __restrict__ f,
    const float* __restrict__ coords,
    const float* __restrict__ anchors,
    const float* __restrict__ gammas,
    const float* __restrict__ norms,
    float* __restrict__ ws,
    int B, int N, int M, int NSEG, int applyNorm)
{
    const int mtiles = M / 256;
    const int tile = blockIdx.x;          // over B * (M/256)
    const int seg  = blockIdx.y;          // N-segment
    const int b    = tile / mtiles;
    const int m    = (tile - b * mtiles) * 256 + threadIdx.x;
    const int bm   = b * M + m;

    const float ax = anchors[(size_t)bm * 3 + 0];
    const float ay = anchors[(size_t)bm * 3 + 1];
    const float az = anchors[(size_t)bm * 3 + 2];

    // Root-basis constants -log2(e)*gamma_k for positions 0..15 (uniform->SGPR)
    v2f c[8];
#pragma unroll
    for (int j = 0; j < 8; ++j) {
        c[j].x = -L2E * gammas[POS2K[2 * j + 0] - 1];
        c[j].y = -L2E * gammas[POS2K[2 * j + 1] - 1];
    }

    v2f acc[16];
#pragma unroll
    for (int j = 0; j < 16; ++j) acc[j] = (v2f)(0.0f);

    const float* __restrict__ fb = f + (size_t)b * N;
    const float* __restrict__ cb = coords + (size_t)b * N * 3;

    const int n0 = seg * NSEG;            // NSEG is a multiple of 4
    const int groups = NSEG / 4;
    const float4* __restrict__ cb4 = (const float4*)(cb + (size_t)n0 * 3);
    const float4* __restrict__ fb4 = (const float4*)(fb + n0);

    // double-buffered wave-uniform batch: 4 points = 3 coord float4 + 1 f float4
    float4 C0 = cb4[0], C1 = cb4[1], C2 = cb4[2], F = fb4[0];

    for (int g = 0; g < groups; ++g) {
        const float4 c0 = C0, c1 = C1, c2 = C2, fq = F;
        const int gn = (g + 1 < groups) ? (g + 1) : g;
        C0 = cb4[3 * gn + 0];
        C1 = cb4[3 * gn + 1];
        C2 = cb4[3 * gn + 2];
        F  = fb4[gn];

        // 4 points' squared distances
        float d2q[4], fvq[4] = { fq.x, fq.y, fq.z, fq.w };
        { const float dx = ax - c0.x, dy = ay - c0.y, dz = az - c0.z;
          d2q[0] = fmaf(dx, dx, fmaf(dy, dy, dz * dz)); }
        { const float dx = ax - c0.w, dy = ay - c1.x, dz = az - c1.y;
          d2q[1] = fmaf(dx, dx, fmaf(dy, dy, dz * dz)); }
        { const float dx = ax - c1.z, dy = ay - c1.w, dz = az - c2.x;
          d2q[2] = fmaf(dx, dx, fmaf(dy, dy, dz * dz)); }
        { const float dx = ax - c2.y, dy = ay - c2.z, dz = az - c2.w;
          d2q[3] = fmaf(dx, dx, fmaf(dy, dy, dz * dz)); }

#pragma unroll
        for (int q = 0; q < 4; ++q) {
            const v2f d2v = (v2f)(d2q[q]);
            const v2f fv2 = (v2f)(fvq[q]);

            // --- A half: tree-root pairs j=0..3, issue their exps first ---
            v2f eA[4];
#pragma unroll
            for (int j = 0; j < 4; ++j) {
                const v2f a = d2v * c[j];
                eA[j].x = exp2f_fast(a.x);
                eA[j].y = exp2f_fast(a.y);
            }
            // --- B half: leaf pairs j=4..7 — exps issue while A's are in flight
            v2f eB[4];
#pragma unroll
            for (int j = 0; j < 4; ++j) {
                const v2f a = d2v * c[4 + j];
                eB[j].x = exp2f_fast(a.x);
                eB[j].y = exp2f_fast(a.y);
            }

            // derive from A (first consumer of eA is ~8 exps after issue)
            v2f D0, D1, D2, D3, Q0, Q1, T0;
            { v2f t = eA[0] * eA[0]; D0 = t * t; }   // (E16,E12)
            { v2f t = eA[1] * eA[1]; D1 = t * t; }   // (E14,E10)
            { v2f t = eA[2] * eA[2]; D2 = t * t; }   // (E15,E11)
            { v2f t = eA[3] * eA[3]; D3 = t * t; }   // (E13,E9)
            { v2f t = D0 * D0;       Q0 = t * t; }   // (E8,E6)
            { v2f t = D1 * D1;       Q1 = t * t; }   // (E7,E5)
            { v2f t = Q0 * Q0;       T0 = t * t; }   // (E4,E3)
            const float u1 = T0.x * T0.x;
            const float E2 = u1 * u1;                // E2 = E4^4
            const float u2 = E2 * E2;
            const float E1 = u2 * u2;                // E1 = E2^4

            // accumulate: A roots, derived, then B leaves (B consumed last)
#pragma unroll
            for (int j = 0; j < 4; ++j)
                acc[j] = VFMA(eA[j], fv2, acc[j]);
            acc[8]  = VFMA(D0, fv2, acc[8]);
            acc[9]  = VFMA(D1, fv2, acc[9]);
            acc[10] = VFMA(D2, fv2, acc[10]);
            acc[11] = VFMA(D3, fv2, acc[11]);
            acc[12] = VFMA(Q0, fv2, acc[12]);
            acc[13] = VFMA(Q1, fv2, acc[13]);
            acc[14] = VFMA(T0, fv2, acc[14]);
            acc[15].x = fmaf(E2, fvq[q], acc[15].x);
            acc[15].y = fmaf(E1, fvq[q], acc[15].y);
#pragma unroll
            for (int j = 0; j < 4; ++j)
                acc[4 + j] = VFMA(eB[j], fv2, acc[4 + j]);
        }
    }

    if (applyNorm) {
        // single-segment path: un-permute + normalize here
        float tmp[NB];
#pragma unroll
        for (int j = 0; j < 16; ++j) { tmp[2 * j] = acc[j].x; tmp[2 * j + 1] = acc[j].y; }
#pragma unroll
        for (int p = 0; p < NB; ++p) {
            const int k = POS2K[p];
            ws[(size_t)bm * NB + (k - 1)] = tmp[p] / norms[k - 1];
        }
    } else {
        // partials stay in permuted position order: contiguous v2f stores
        v2f* __restrict__ w = (v2f*)(ws + ((size_t)seg * (B * M) + bm) * NB);
#pragma unroll
        for (int j = 0; j < 16; ++j) w[j] = acc[j];
    }
}

// Second pass: sum S partials (float4 reads), un-permute, apply 1/norm.
__global__ __launch_bounds__(256) void gp_reduce(
    const float4* __restrict__ ws,
    const float* __restrict__ norms,
    float* __restrict__ out,
    int BM, int S)
{
    const int t = blockIdx.x * blockDim.x + threadIdx.x;   // over BM * NB/4
    if (t >= BM * (NB / 4)) return;
    const int bm = t >> 3;
    const int j  = t & 7;                                   // float4 group
    const size_t stride = (size_t)BM * (NB / 4);
    float4 s = make_float4(0.f, 0.f, 0.f, 0.f);
    for (int i = 0; i < S; ++i) {
        const float4 v = ws[(size_t)i * stride + t];
        s.x += v.x; s.y += v.y; s.z += v.z; s.w += v.w;
    }
    const float sv[4] = { s.x, s.y, s.z, s.w };
#pragma unroll
    for (int c = 0; c < 4; ++c) {
        const int k = POS2K[4 * j + c];
        out[(size_t)bm * NB + (k - 1)] = sv[c] / norms[k - 1];
    }
}

extern "C" void kernel_launch(void* const* d_in, const int* in_sizes, int n_in,
                              void* d_out, int out_size, void* d_ws, size_t ws_size,
                              hipStream_t stream) {
    const float* f       = (const float*)d_in[0];
    const float* coords  = (const float*)d_in[1];
    const float* anchors = (const float*)d_in[2];
    const float* gammas  = (const float*)d_in[3];
    const float* norms   = (const float*)d_in[4];
    float* out = (float*)d_out;

    const int B = 2, N = 8192, M = 4096;
    const int BM = B * M;

    // Segments of N sized by workspace capacity (partials: S*BM*NB floats).
    int S = (int)(ws_size / ((size_t)BM * NB * sizeof(float)));
    if (S > 64) S = 64;
    int s2 = 1; while (s2 * 2 <= S) s2 *= 2;   // power of two dividing N
    S = (S >= 1) ? s2 : 0;

    if (S >= 2) {
        const int NSEG = N / S;
        dim3 grid(B * (M / 256), S);
        gp_main<<<grid, 256, 0, stream>>>(f, coords, anchors, gammas, norms,
                                          (float*)d_ws, B, N, M, NSEG, 0);
        const int total = BM * (NB / 4);
        gp_reduce<<<(total + 255) / 256, 256, 0, stream>>>(
            (const float4*)d_ws, norms, out, BM, S);
    } else {
        dim3 grid(B * (M / 256), 1);
        gp_main<<<grid, 256, 0, stream>>>(f, coords, anchors, gammas, norms,
                                          out, B, N, M, N, 1);
    }
}

// Round 8
// 181.906 us; speedup vs baseline: 1.1282x; 1.1282x over previous
//
#include <hip/hip_runtime.h>

#define NB 32
#define L2E 1.4426950408889634f

typedef float v2f __attribute__((ext_vector_type(2)));

static __device__ __forceinline__ float exp2f_fast(float x) {
#if __has_builtin(__builtin_amdgcn_exp2f)
    return __builtin_amdgcn_exp2f(x);
#else
    return __expf(x * 0.6931471805599453f);
#endif
}

#if __has_builtin(__builtin_elementwise_fma)
#define VFMA(a, b, c) __builtin_elementwise_fma(a, b, c)
#else
static __device__ inline v2f VFMA(v2f a, v2f b, v2f c) {
    v2f r; r.x = fmaf(a.x, b.x, c.x); r.y = fmaf(a.y, b.y, c.y); return r;
}
#endif

// Storage position p (0..31) -> basis index k (1-based). Pairing chosen so
// every 4th-power derivation maps a whole v2f pair onto a whole v2f pair
// (E_k = E_{2k}^4 since gamma_k = 32/k^2 exactly): zero shuffles.
// Positions 0..7 ("A half", pairs j=0..3) are the roots feeding the whole
// derive tree; positions 8..15 ("B half", j=4..7) are leaf roots.
static __device__ const int POS2K[NB] = {
    32,24, 28,20, 30,22, 26,18, 31,23, 29,21, 27,19, 25,17,
    16,12, 14,10, 15,11, 13,9,  8,6,   7,5,   4,3,   2,1 };

// NOTE: min-waves arg must stay 4. (256,8) caps VGPR at 32 -> acc[16] v2f
// spills to scratch: R7 measured FETCH 2->43MB, WRITE 64->237MB, +13% time.
__global__ __launch_bounds__(256, 4) void gp_main(
    const float* __restrict__ f,
    const float* __restrict__ coords,
    const float* __restrict__ anchors,
    const float* __restrict__ gammas,
    const float* __restrict__ norms,
    float* __restrict__ ws,
    int B, int N, int M, int NSEG, int applyNorm)
{
    const int mtiles = M / 256;
    const int tile = blockIdx.x;          // over B * (M/256)
    const int seg  = blockIdx.y;          // N-segment
    const int b    = tile / mtiles;
    const int m    = (tile - b * mtiles) * 256 + threadIdx.x;
    const int bm   = b * M + m;

    const float ax = anchors[(size_t)bm * 3 + 0];
    const float ay = anchors[(size_t)bm * 3 + 1];
    const float az = anchors[(size_t)bm * 3 + 2];

    // Root-basis constants -log2(e)*gamma_k for positions 0..15 (uniform->SGPR)
    v2f c[8];
#pragma unroll
    for (int j = 0; j < 8; ++j) {
        c[j].x = -L2E * gammas[POS2K[2 * j + 0] - 1];
        c[j].y = -L2E * gammas[POS2K[2 * j + 1] - 1];
    }

    v2f acc[16];
#pragma unroll
    for (int j = 0; j < 16; ++j) acc[j] = (v2f)(0.0f);

    const float* __restrict__ fb = f + (size_t)b * N;
    const float* __restrict__ cb = coords + (size_t)b * N * 3;

    const int n0 = seg * NSEG;            // NSEG is a multiple of 4
    const int groups = NSEG / 4;
    const float4* __restrict__ cb4 = (const float4*)(cb + (size_t)n0 * 3);
    const float4* __restrict__ fb4 = (const float4*)(fb + n0);

    // double-buffered wave-uniform batch: 4 points = 3 coord float4 + 1 f float4
    float4 C0 = cb4[0], C1 = cb4[1], C2 = cb4[2], F = fb4[0];

    for (int g = 0; g < groups; ++g) {
        const float4 c0 = C0, c1 = C1, c2 = C2, fq = F;
        const int gn = (g + 1 < groups) ? (g + 1) : g;
        C0 = cb4[3 * gn + 0];
        C1 = cb4[3 * gn + 1];
        C2 = cb4[3 * gn + 2];
        F  = fb4[gn];

        // 4 points' squared distances
        float d2q[4], fvq[4] = { fq.x, fq.y, fq.z, fq.w };
        { const float dx = ax - c0.x, dy = ay - c0.y, dz = az - c0.z;
          d2q[0] = fmaf(dx, dx, fmaf(dy, dy, dz * dz)); }
        { const float dx = ax - c0.w, dy = ay - c1.x, dz = az - c1.y;
          d2q[1] = fmaf(dx, dx, fmaf(dy, dy, dz * dz)); }
        { const float dx = ax - c1.z, dy = ay - c1.w, dz = az - c2.x;
          d2q[2] = fmaf(dx, dx, fmaf(dy, dy, dz * dz)); }
        { const float dx = ax - c2.y, dy = ay - c2.z, dz = az - c2.w;
          d2q[3] = fmaf(dx, dx, fmaf(dy, dy, dz * dz)); }

#pragma unroll
        for (int q = 0; q < 4; ++q) {
            const v2f d2v = (v2f)(d2q[q]);
            const v2f fv2 = (v2f)(fvq[q]);

            // --- A half: tree-root pairs j=0..3, issue their exps first ---
            v2f eA[4];
#pragma unroll
            for (int j = 0; j < 4; ++j) {
                const v2f a = d2v * c[j];
                eA[j].x = exp2f_fast(a.x);
                eA[j].y = exp2f_fast(a.y);
            }
            // --- B half: leaf pairs j=4..7 — exps issue while A's are in flight
            v2f eB[4];
#pragma unroll
            for (int j = 0; j < 4; ++j) {
                const v2f a = d2v * c[4 + j];
                eB[j].x = exp2f_fast(a.x);
                eB[j].y = exp2f_fast(a.y);
            }

            // derive from A (first consumer of eA is ~8 exps after issue)
            v2f D0, D1, D2, D3, Q0, Q1, T0;
            { v2f t = eA[0] * eA[0]; D0 = t * t; }   // (E16,E12)
            { v2f t = eA[1] * eA[1]; D1 = t * t; }   // (E14,E10)
            { v2f t = eA[2] * eA[2]; D2 = t * t; }   // (E15,E11)
            { v2f t = eA[3] * eA[3]; D3 = t * t; }   // (E13,E9)
            { v2f t = D0 * D0;       Q0 = t * t; }   // (E8,E6)
            { v2f t = D1 * D1;       Q1 = t * t; }   // (E7,E5)
            { v2f t = Q0 * Q0;       T0 = t * t; }   // (E4,E3)
            const float u1 = T0.x * T0.x;
            const float E2 = u1 * u1;                // E2 = E4^4
            const float u2 = E2 * E2;
            const float E1 = u2 * u2;                // E1 = E2^4

            // accumulate: A roots, derived, then B leaves (B consumed last)
#pragma unroll
            for (int j = 0; j < 4; ++j)
                acc[j] = VFMA(eA[j], fv2, acc[j]);
            acc[8]  = VFMA(D0, fv2, acc[8]);
            acc[9]  = VFMA(D1, fv2, acc[9]);
            acc[10] = VFMA(D2, fv2, acc[10]);
            acc[11] = VFMA(D3, fv2, acc[11]);
            acc[12] = VFMA(Q0, fv2, acc[12]);
            acc[13] = VFMA(Q1, fv2, acc[13]);
            acc[14] = VFMA(T0, fv2, acc[14]);
            acc[15].x = fmaf(E2, fvq[q], acc[15].x);
            acc[15].y = fmaf(E1, fvq[q], acc[15].y);
#pragma unroll
            for (int j = 0; j < 4; ++j)
                acc[4 + j] = VFMA(eB[j], fv2, acc[4 + j]);
        }
    }

    if (applyNorm) {
        // single-segment path: un-permute + normalize here
        float tmp[NB];
#pragma unroll
        for (int j = 0; j < 16; ++j) { tmp[2 * j] = acc[j].x; tmp[2 * j + 1] = acc[j].y; }
#pragma unroll
        for (int p = 0; p < NB; ++p) {
            const int k = POS2K[p];
            ws[(size_t)bm * NB + (k - 1)] = tmp[p] / norms[k - 1];
        }
    } else {
        // partials stay in permuted position order: contiguous v2f stores
        v2f* __restrict__ w = (v2f*)(ws + ((size_t)seg * (B * M) + bm) * NB);
#pragma unroll
        for (int j = 0; j < 16; ++j) w[j] = acc[j];
    }
}

// Second pass: sum S partials (float4 reads), un-permute, apply 1/norm.
__global__ __launch_bounds__(256) void gp_reduce(
    const float4* __restrict__ ws,
    const float* __restrict__ norms,
    float* __restrict__ out,
    int BM, int S)
{
    const int t = blockIdx.x * blockDim.x + threadIdx.x;   // over BM * NB/4
    if (t >= BM * (NB / 4)) return;
    const int bm = t >> 3;
    const int j  = t & 7;                                   // float4 group
    const size_t stride = (size_t)BM * (NB / 4);
    float4 s = make_float4(0.f, 0.f, 0.f, 0.f);
    for (int i = 0; i < S; ++i) {
        const float4 v = ws[(size_t)i * stride + t];
        s.x += v.x; s.y += v.y; s.z += v.z; s.w += v.w;
    }
    const float sv[4] = { s.x, s.y, s.z, s.w };
#pragma unroll
    for (int c = 0; c < 4; ++c) {
        const int k = POS2K[4 * j + c];
        out[(size_t)bm * NB + (k - 1)] = sv[c] / norms[k - 1];
    }
}

extern "C" void kernel_launch(void* const* d_in, const int* in_sizes, int n_in,
                              void* d_out, int out_size, void* d_ws, size_t ws_size,
                              hipStream_t stream) {
    const float* f       = (const float*)d_in[0];
    const float* coords  = (const float*)d_in[1];
    const float* anchors = (const float*)d_in[2];
    const float* gammas  = (const float*)d_in[3];
    const float* norms   = (const float*)d_in[4];
    float* out = (float*)d_out;

    const int B = 2, N = 8192, M = 4096;
    const int BM = B * M;

    // Segments of N sized by workspace capacity (partials: S*BM*NB floats).
    int S = (int)(ws_size / ((size_t)BM * NB * sizeof(float)));
    if (S > 64) S = 64;
    int s2 = 1; while (s2 * 2 <= S) s2 *= 2;   // power of two dividing N
    S = (S >= 1) ? s2 : 0;

    if (S >= 2) {
        const int NSEG = N / S;
        dim3 grid(B * (M / 256), S);
        gp_main<<<grid, 256, 0, stream>>>(f, coords, anchors, gammas, norms,
                                          (float*)d_ws, B, N, M, NSEG, 0);
        const int total = BM * (NB / 4);
        gp_reduce<<<(total + 255) / 256, 256, 0, stream>>>(
            (const float4*)d_ws, norms, out, BM, S);
    } else {
        dim3 grid(B * (M / 256), 1);
        gp_main<<<grid, 256, 0, stream>>>(f, coords, anchors, gammas, norms,
                                          out, B, N, M, N, 1);
    }
}